// Round 1
// baseline (1740.929 us; speedup 1.0000x reference)
//
#include <hip/hip_runtime.h>
#include <math.h>

// Problem constants (fixed by setup_inputs): B=64, J=21, D=H=W=64.
#define NB      64
#define NJ      21
#define VOL     262144          // 64*64*64 elements per (b,j)
#define THREADS 256
#define NV4     (VOL / 4)       // 65536 float4s per volume
#define ITERS   (NV4 / THREADS) // 256 float4s per thread

__device__ __forceinline__ void merge5(float& m, float& s, float& sx, float& sy, float& sz,
                                       float m2, float s2, float sx2, float sy2, float sz2) {
    float nm = fmaxf(m, m2);
    float a  = __expf(m  - nm);
    float b  = __expf(m2 - nm);
    s  = s  * a + s2  * b;
    sx = sx * a + sx2 * b;
    sy = sy * a + sy2 * b;
    sz = sz * a + sz2 * b;
    m  = nm;
}

__global__ __launch_bounds__(THREADS)
void jll_kernel(const float* __restrict__ hm,
                const float* __restrict__ gt_coord,
                const float* __restrict__ gt_vis,
                float* __restrict__ out) {
    const int bj  = blockIdx.x;          // 0..1343  == b*NJ + j
    const int tid = threadIdx.x;

    const float4* vol = (const float4*)(hm + (size_t)bj * VOL);

    // Online softmax state: running max m, Σe, Σe*x, Σe*y, Σe*z
    float m = -3.0e38f, s = 0.f, sx = 0.f, sy = 0.f, sz = 0.f;

#pragma unroll 4
    for (int it = 0; it < ITERS; ++it) {
        const int vidx = it * THREADS + tid;     // float4 index within volume
        float4 v = vol[vidx];

        // element linear index l = vidx*4 ; w = l&63, h = (l>>6)&63, d = l>>12
        const float wb = (float)((vidx & 15) << 2);   // base w of this float4
        const float hb = (float)((vidx >> 4) & 63);
        const float db = (float)(vidx >> 10);

        float vm = fmaxf(fmaxf(v.x, v.y), fmaxf(v.z, v.w));
        float nm = fmaxf(m, vm);
        float scale = __expf(m - nm);
        float e0 = __expf(v.x - nm);
        float e1 = __expf(v.y - nm);
        float e2 = __expf(v.z - nm);
        float e3 = __expf(v.w - nm);
        float es = e0 + e1 + e2 + e3;
        float ex = e0 * wb + e1 * (wb + 1.f) + e2 * (wb + 2.f) + e3 * (wb + 3.f);

        s  = s  * scale + es;
        sx = sx * scale + ex;
        sy = sy * scale + es * hb;
        sz = sz * scale + es * db;
        m  = nm;
    }

    // Wave (64-lane) butterfly reduction
#pragma unroll
    for (int off = 32; off >= 1; off >>= 1) {
        float m2  = __shfl_xor(m,  off, 64);
        float s2  = __shfl_xor(s,  off, 64);
        float sx2 = __shfl_xor(sx, off, 64);
        float sy2 = __shfl_xor(sy, off, 64);
        float sz2 = __shfl_xor(sz, off, 64);
        merge5(m, s, sx, sy, sz, m2, s2, sx2, sy2, sz2);
    }

    // Cross-wave merge via LDS (4 waves of 64)
    __shared__ float red[4][5];
    const int wave = tid >> 6;
    const int lane = tid & 63;
    if (lane == 0) {
        red[wave][0] = m; red[wave][1] = s; red[wave][2] = sx;
        red[wave][3] = sy; red[wave][4] = sz;
    }
    __syncthreads();

    if (tid == 0) {
#pragma unroll
        for (int w = 1; w < 4; ++w) {
            merge5(m, s, sx, sy, sz,
                   red[w][0], red[w][1], red[w][2], red[w][3], red[w][4]);
        }
        const float inv = 1.0f / s;
        const float x = sx * inv * (1.0f / 64.0f) - 0.5f;
        const float y = sy * inv * (1.0f / 64.0f) - 0.5f;
        const float z = sz * inv * (1.0f / 64.0f) - 0.5f;

        const int b = bj / NJ;
        const int j = bj - b * NJ;
        const float* gc = gt_coord + b * (NJ * 3) + j * 3;
        const float* gv = gt_vis   + b * (NJ * 3) + j * 3;

        float contrib = (fabsf(x - gc[0]) * gv[0] +
                         fabsf(y - gc[1]) * gv[1] +
                         fabsf(z - gc[2]) * gv[2]) * (1.0f / (float)NB);
        atomicAdd(out, contrib);
    }
}

extern "C" void kernel_launch(void* const* d_in, const int* in_sizes, int n_in,
                              void* d_out, int out_size, void* d_ws, size_t ws_size,
                              hipStream_t stream) {
    const float* hm  = (const float*)d_in[0];
    const float* gtc = (const float*)d_in[1];
    const float* gtv = (const float*)d_in[2];
    float* out = (float*)d_out;

    // Harness poisons d_out to 0xAA before every launch — zero it on-stream.
    hipMemsetAsync(out, 0, sizeof(float) * out_size, stream);

    jll_kernel<<<NB * NJ, THREADS, 0, stream>>>(hm, gtc, gtv, out);
}